// Round 1
// baseline (499.394 us; speedup 1.0000x reference)
//
#include <hip/hip_runtime.h>
#include <hip/hip_bf16.h>
#include <cstdint>

#define NH 12
#define DH 64
#define TSEQ 4096
#define BATCH 2
#define CDIM 768
#define MROWS (BATCH*TSEQ)

typedef __bf16 bf16x8 __attribute__((ext_vector_type(8)));
typedef bf16x8 bf16x8_a __attribute__((may_alias));
typedef float f32x4 __attribute__((ext_vector_type(4)));

__device__ __forceinline__ uint16_t f2bu(float f) {
  uint32_t u = __float_as_uint(f);
  u += 0x7fffu + ((u >> 16) & 1u);
  return (uint16_t)(u >> 16);
}

__device__ __forceinline__ void gload_lds16(const void* g, void* l) {
  __builtin_amdgcn_global_load_lds(
      (const __attribute__((address_space(1))) void*)g,
      (__attribute__((address_space(3))) void*)l, 16, 0, 0);
}

// ---------------- cast fp32 -> bf16 (vectorized) ----------------
__global__ void cast_f32_bf16(const float* __restrict__ in, uint16_t* __restrict__ out, int n4) {
  int i = blockIdx.x * blockDim.x + threadIdx.x;
  int stride = gridDim.x * blockDim.x;
  for (; i < n4; i += stride) {
    float4 v = ((const float4*)in)[i];
    ushort4 o;
    o.x = f2bu(v.x); o.y = f2bu(v.y); o.z = f2bu(v.z); o.w = f2bu(v.w);
    ((ushort4*)out)[i] = o;
  }
}

// ---------------- transpose + cast: W[K][N] f32 -> Wt[N][K] bf16 ----------------
__global__ void transpose_cast(const float* __restrict__ w, uint16_t* __restrict__ wt, int K, int N) {
  __shared__ float tile[32][33];
  int kb = blockIdx.x * 32, nb = blockIdx.y * 32;
  int tx = threadIdx.x & 31, ty = threadIdx.x >> 5;
  #pragma unroll
  for (int r = ty; r < 32; r += 8) tile[r][tx] = w[(size_t)(kb + r) * N + nb + tx];
  __syncthreads();
  #pragma unroll
  for (int r = ty; r < 32; r += 8) wt[(size_t)(nb + r) * K + kb + tx] = f2bu(tile[tx][r]);
}

// ---------------- GEMM: C[M,N] = A[M,K](bf16) @ Bt[N,K]^T(bf16) + bias ----------------
// MODE 0: scatter into Q/K/V [B,H,T,Dh] bf16.  MODE 1: write fp32 to outf [M,N].
template <int MODE>
__global__ __launch_bounds__(256) void gemm_bt(
    const uint16_t* __restrict__ A, const uint16_t* __restrict__ Bt,
    const float* __restrict__ bias,
    uint16_t* __restrict__ q, uint16_t* __restrict__ k, uint16_t* __restrict__ v,
    float* __restrict__ outf, int N, int K) {
  __shared__ uint16_t As[128 * 32];
  __shared__ uint16_t Bs[128 * 32];
  int tid = threadIdx.x;
  int w = tid >> 6, l = tid & 63;
  int lg = l >> 4, lr = l & 15;
  int mb = blockIdx.x * 128, nb = blockIdx.y * 128;
  int wr = (w >> 1) * 64, wc = (w & 1) * 64;
  f32x4 acc[4][4] = {};
  int srow = tid >> 2, scol = (tid & 3) * 8;
  const uint16_t* Ag = A + (size_t)(mb + srow) * K + scol;
  const uint16_t* Bg = Bt + (size_t)(nb + srow) * K + scol;
  char* AsB = (char*)As + (size_t)w * 1024;
  char* BsB = (char*)Bs + (size_t)w * 1024;
  size_t rowskip = (size_t)64 * K;
  for (int kb = 0; kb < K; kb += 32) {
    __syncthreads();
    gload_lds16(Ag + kb, AsB);
    gload_lds16(Ag + kb + rowskip, AsB + 4096);
    gload_lds16(Bg + kb, BsB);
    gload_lds16(Bg + kb + rowskip, BsB + 4096);
    __syncthreads();
    bf16x8 af[4], bfr[4];
    #pragma unroll
    for (int i = 0; i < 4; ++i)
      af[i] = *(const bf16x8_a*)(const void*)(As + (wr + i * 16 + lr) * 32 + lg * 8);
    #pragma unroll
    for (int i = 0; i < 4; ++i)
      bfr[i] = *(const bf16x8_a*)(const void*)(Bs + (wc + i * 16 + lr) * 32 + lg * 8);
    #pragma unroll
    for (int mi = 0; mi < 4; ++mi)
      #pragma unroll
      for (int ni = 0; ni < 4; ++ni)
        acc[mi][ni] = __builtin_amdgcn_mfma_f32_16x16x32_bf16(af[mi], bfr[ni], acc[mi][ni], 0, 0, 0);
  }
  #pragma unroll
  for (int mi = 0; mi < 4; ++mi) {
    #pragma unroll
    for (int ni = 0; ni < 4; ++ni) {
      #pragma unroll
      for (int j = 0; j < 4; ++j) {
        int gm = mb + wr + mi * 16 + lg * 4 + j;
        int gn = nb + wc + ni * 16 + lr;
        float val = acc[mi][ni][j] + bias[gn];
        if (MODE == 0) {
          int which = gn / CDIM;
          int cc = gn - which * CDIM;
          int h = cc >> 6, d = cc & 63;
          int b = gm >> 12, t = gm & 4095;
          uint16_t* dst = (which == 0) ? q : (which == 1) ? k : v;
          dst[(((size_t)(b * NH + h)) * TSEQ + t) * DH + d] = f2bu(val);
        } else {
          outf[(size_t)gm * N + gn] = val;
        }
      }
    }
  }
}

// ---------------- flash attention (causal), QBLK=64 (16 rows/wave), KVBLK=64 ----------------
__global__ __launch_bounds__(256) void attn_fwd(
    const uint16_t* __restrict__ Q, const uint16_t* __restrict__ K,
    const uint16_t* __restrict__ V, uint16_t* __restrict__ O) {
  int qt = blockIdx.x, bh = blockIdx.y;
  int b = bh / NH, h = bh - b * NH;
  size_t base = (size_t)bh * TSEQ * DH;
  int tid = threadIdx.x, w = tid >> 6, l = tid & 63;
  int lg = l >> 4, lr = l & 15;
  int qbase = qt * 64;
  __shared__ uint16_t Ks[64 * 64];
  __shared__ uint16_t Vt[64 * 64];
  __shared__ uint16_t Ps[4][16 * 64];
  int qrow = qbase + w * 16 + lr;
  bf16x8 qf0 = *(const bf16x8_a*)(const void*)(Q + base + (size_t)qrow * DH + lg * 8);
  bf16x8 qf1 = *(const bf16x8_a*)(const void*)(Q + base + (size_t)qrow * DH + 32 + lg * 8);
  f32x4 oacc[4] = {};
  float mj[4] = {-1e30f, -1e30f, -1e30f, -1e30f};
  float lj[4] = {0.f, 0.f, 0.f, 0.f};
  const uint16_t* Kgb = K + base + (size_t)(tid >> 3) * DH + (tid & 7) * 8;
  char* KsB = (char*)Ks + (size_t)w * 1024;
  int vr = tid >> 2, vd0 = (tid & 3) * 16;
  const uint16_t* Vgb = V + base + (size_t)vr * DH + vd0;
  uint16_t* pw = Ps[w];
  for (int kt = 0; kt <= qt; ++kt) {
    __syncthreads();
    gload_lds16(Kgb + (size_t)kt * 4096, KsB);
    gload_lds16(Kgb + (size_t)kt * 4096 + 2048, KsB + 4096);
    {
      const uint16_t* vg = Vgb + (size_t)kt * 4096;
      bf16x8 v0 = *(const bf16x8_a*)(const void*)(vg);
      bf16x8 v1 = *(const bf16x8_a*)(const void*)(vg + 8);
      #pragma unroll
      for (int jj = 0; jj < 8; ++jj) {
        ((__bf16*)Vt)[(vd0 + jj) * 64 + vr] = v0[jj];
        ((__bf16*)Vt)[(vd0 + 8 + jj) * 64 + vr] = v1[jj];
      }
    }
    __syncthreads();
    // S = Q @ K^T  (D layout: row=(lg*4+j) q-row, col=lr key)
    f32x4 sacc[4];
    #pragma unroll
    for (int ni = 0; ni < 4; ++ni) {
      bf16x8 kf0 = *(const bf16x8_a*)(const void*)(Ks + (ni * 16 + lr) * 64 + lg * 8);
      bf16x8 kf1 = *(const bf16x8_a*)(const void*)(Ks + (ni * 16 + lr) * 64 + 32 + lg * 8);
      f32x4 s = {};
      s = __builtin_amdgcn_mfma_f32_16x16x32_bf16(qf0, kf0, s, 0, 0, 0);
      s = __builtin_amdgcn_mfma_f32_16x16x32_bf16(qf1, kf1, s, 0, 0, 0);
      sacc[ni] = s;
    }
    int kb0 = kt * 64;
    float rowmax[4] = {-1e30f, -1e30f, -1e30f, -1e30f};
    #pragma unroll
    for (int ni = 0; ni < 4; ++ni) {
      #pragma unroll
      for (int j = 0; j < 4; ++j) {
        float sv = sacc[ni][j] * 0.125f;
        int kg = kb0 + ni * 16 + lr;
        int qg = qbase + w * 16 + lg * 4 + j;
        sv = (kg <= qg) ? sv : -1e30f;
        sacc[ni][j] = sv;
        rowmax[j] = fmaxf(rowmax[j], sv);
      }
    }
    #pragma unroll
    for (int j = 0; j < 4; ++j) {
      float r = rowmax[j];
      #pragma unroll
      for (int msk = 1; msk < 16; msk <<= 1) r = fmaxf(r, __shfl_xor(r, msk, 64));
      float mn = fmaxf(mj[j], r);
      float c = __expf(mj[j] - mn);
      float rs = 0.f;
      #pragma unroll
      for (int ni = 0; ni < 4; ++ni) {
        float p = __expf(sacc[ni][j] - mn);
        sacc[ni][j] = p;
        rs += p;
      }
      #pragma unroll
      for (int msk = 1; msk < 16; msk <<= 1) rs += __shfl_xor(rs, msk, 64);
      lj[j] = lj[j] * c + rs;
      mj[j] = mn;
      #pragma unroll
      for (int nd = 0; nd < 4; ++nd) oacc[nd][j] *= c;
    }
    // P -> per-wave LDS tile [16 q][64 k] (layout fix for A-fragment)
    #pragma unroll
    for (int ni = 0; ni < 4; ++ni)
      #pragma unroll
      for (int j = 0; j < 4; ++j)
        pw[(lg * 4 + j) * 64 + ni * 16 + lr] = f2bu(sacc[ni][j]);
    bf16x8 pf0 = *(const bf16x8_a*)(const void*)(pw + lr * 64 + lg * 8);
    bf16x8 pf1 = *(const bf16x8_a*)(const void*)(pw + lr * 64 + 32 + lg * 8);
    #pragma unroll
    for (int nd = 0; nd < 4; ++nd) {
      bf16x8 vf0 = *(const bf16x8_a*)(const void*)(Vt + (nd * 16 + lr) * 64 + lg * 8);
      bf16x8 vf1 = *(const bf16x8_a*)(const void*)(Vt + (nd * 16 + lr) * 64 + 32 + lg * 8);
      oacc[nd] = __builtin_amdgcn_mfma_f32_16x16x32_bf16(pf0, vf0, oacc[nd], 0, 0, 0);
      oacc[nd] = __builtin_amdgcn_mfma_f32_16x16x32_bf16(pf1, vf1, oacc[nd], 0, 0, 0);
    }
  }
  #pragma unroll
  for (int nd = 0; nd < 4; ++nd) {
    #pragma unroll
    for (int j = 0; j < 4; ++j) {
      int t = qbase + w * 16 + lg * 4 + j;
      float val = oacc[nd][j] / lj[j];
      O[((size_t)(b * TSEQ + t)) * CDIM + h * DH + nd * 16 + lr] = f2bu(val);
    }
  }
}

extern "C" void kernel_launch(void* const* d_in, const int* in_sizes, int n_in,
                              void* d_out, int out_size, void* d_ws, size_t ws_size,
                              hipStream_t stream) {
  const float* x    = (const float*)d_in[0];
  const float* Wqkv = (const float*)d_in[1];
  const float* bqkv = (const float*)d_in[2];
  const float* Wout = (const float*)d_in[3];
  const float* bout = (const float*)d_in[4];
  float* out = (float*)d_out;
  char* ws = (char*)d_ws;

  uint16_t* Xb    = (uint16_t*)(ws + 0);          // 8192*768*2   = 12,582,912
  uint16_t* Wqkvt = (uint16_t*)(ws + 12582912);   // 2304*768*2   =  3,538,944
  uint16_t* Woutt = (uint16_t*)(ws + 16121856);   // 768*768*2    =  1,179,648
  uint16_t* Qb    = (uint16_t*)(ws + 17301504);   // 12,582,912
  uint16_t* Kb    = (uint16_t*)(ws + 29884416);   // 12,582,912
  uint16_t* Vb    = (uint16_t*)(ws + 42467328);   // 12,582,912
  uint16_t* Ob    = (uint16_t*)(ws + 55050240);   // 12,582,912 (end 67,633,152)

  cast_f32_bf16<<<2048, 256, 0, stream>>>(x, Xb, (MROWS * CDIM) / 4);
  transpose_cast<<<dim3(24, 72), 256, 0, stream>>>(Wqkv, Wqkvt, 768, 2304);
  transpose_cast<<<dim3(24, 24), 256, 0, stream>>>(Wout, Woutt, 768, 768);
  gemm_bt<0><<<dim3(64, 18), 256, 0, stream>>>(Xb, Wqkvt, bqkv, Qb, Kb, Vb, nullptr, 2304, 768);
  attn_fwd<<<dim3(64, 24), 256, 0, stream>>>(Qb, Kb, Vb, Ob);
  gemm_bt<1><<<dim3(64, 6), 256, 0, stream>>>(Ob, Woutt, bout, nullptr, nullptr, nullptr, out, 768, 768);
}

// Round 2
// 236.750 us; speedup vs baseline: 2.1094x; 2.1094x over previous
//
#include <hip/hip_runtime.h>
#include <hip/hip_bf16.h>
#include <cstdint>

#define NH 12
#define DH 64
#define TSEQ 4096
#define BATCH 2
#define CDIM 768
#define MROWS (BATCH*TSEQ)

typedef __bf16 bf16x8 __attribute__((ext_vector_type(8)));
typedef bf16x8 bf16x8_a __attribute__((may_alias));
typedef float f32x4 __attribute__((ext_vector_type(4)));

__device__ __forceinline__ uint16_t f2bu(float f) {
  uint32_t u = __float_as_uint(f);
  u += 0x7fffu + ((u >> 16) & 1u);
  return (uint16_t)(u >> 16);
}

__device__ __forceinline__ void gload_lds16(const void* g, void* l) {
  __builtin_amdgcn_global_load_lds(
      (const __attribute__((address_space(1))) void*)g,
      (__attribute__((address_space(3))) void*)l, 16, 0, 0);
}

// ---------------- cast fp32 -> bf16 (vectorized) ----------------
__global__ void cast_f32_bf16(const float* __restrict__ in, uint16_t* __restrict__ out, int n4) {
  int i = blockIdx.x * blockDim.x + threadIdx.x;
  int stride = gridDim.x * blockDim.x;
  for (; i < n4; i += stride) {
    float4 v = ((const float4*)in)[i];
    ushort4 o;
    o.x = f2bu(v.x); o.y = f2bu(v.y); o.z = f2bu(v.z); o.w = f2bu(v.w);
    ((ushort4*)out)[i] = o;
  }
}

// ---------------- transpose + cast: W[K][N] f32 -> Wt[N][K] bf16 ----------------
__global__ void transpose_cast(const float* __restrict__ w, uint16_t* __restrict__ wt, int K, int N) {
  __shared__ float tile[32][33];
  int kb = blockIdx.x * 32, nb = blockIdx.y * 32;
  int tx = threadIdx.x & 31, ty = threadIdx.x >> 5;
  #pragma unroll
  for (int r = ty; r < 32; r += 8) tile[r][tx] = w[(size_t)(kb + r) * N + nb + tx];
  __syncthreads();
  #pragma unroll
  for (int r = ty; r < 32; r += 8) wt[(size_t)(nb + r) * K + kb + tx] = f2bu(tile[tx][r]);
}

// ---------------- GEMM: C[M,N] = A[M,K](bf16) @ Bt[N,K]^T(bf16) + bias ----------------
// MODE 0: scatter Q (pre-scaled by 0.125*log2e) and K into [B,H,T,Dh]; V into V^T [B,H,Dh,T].
// MODE 1: write fp32 to outf [M,N].
template <int MODE>
__global__ __launch_bounds__(256) void gemm_bt(
    const uint16_t* __restrict__ A, const uint16_t* __restrict__ Bt,
    const float* __restrict__ bias,
    uint16_t* __restrict__ q, uint16_t* __restrict__ k, uint16_t* __restrict__ v,
    float* __restrict__ outf, int N, int K) {
  __shared__ uint16_t As[128 * 32];
  __shared__ uint16_t Bs[128 * 32];
  int tid = threadIdx.x;
  int w = tid >> 6, l = tid & 63;
  int lg = l >> 4, lr = l & 15;
  int mb = blockIdx.x * 128, nb = blockIdx.y * 128;
  int wr = (w >> 1) * 64, wc = (w & 1) * 64;
  f32x4 acc[4][4] = {};
  int srow = tid >> 2, scol = (tid & 3) * 8;
  const uint16_t* Ag = A + (size_t)(mb + srow) * K + scol;
  const uint16_t* Bg = Bt + (size_t)(nb + srow) * K + scol;
  char* AsB = (char*)As + (size_t)w * 1024;
  char* BsB = (char*)Bs + (size_t)w * 1024;
  size_t rowskip = (size_t)64 * K;
  for (int kb = 0; kb < K; kb += 32) {
    __syncthreads();
    gload_lds16(Ag + kb, AsB);
    gload_lds16(Ag + kb + rowskip, AsB + 4096);
    gload_lds16(Bg + kb, BsB);
    gload_lds16(Bg + kb + rowskip, BsB + 4096);
    __syncthreads();
    bf16x8 af[4], bfr[4];
    #pragma unroll
    for (int i = 0; i < 4; ++i)
      af[i] = *(const bf16x8_a*)(const void*)(As + (wr + i * 16 + lr) * 32 + lg * 8);
    #pragma unroll
    for (int i = 0; i < 4; ++i)
      bfr[i] = *(const bf16x8_a*)(const void*)(Bs + (wc + i * 16 + lr) * 32 + lg * 8);
    #pragma unroll
    for (int mi = 0; mi < 4; ++mi)
      #pragma unroll
      for (int ni = 0; ni < 4; ++ni)
        acc[mi][ni] = __builtin_amdgcn_mfma_f32_16x16x32_bf16(af[mi], bfr[ni], acc[mi][ni], 0, 0, 0);
  }
  #pragma unroll
  for (int mi = 0; mi < 4; ++mi) {
    #pragma unroll
    for (int ni = 0; ni < 4; ++ni) {
      if (MODE == 0) {
        int gm0 = mb + wr + mi * 16 + lg * 4;
        int gn = nb + wc + ni * 16 + lr;
        int which = gn / CDIM;
        int cc = gn - which * CDIM;
        int hh = cc >> 6, d = cc & 63;
        float bs = bias[gn];
        if (which == 2) {
          // V^T store: 4 consecutive t at fixed d, packed 8B
          int b0 = gm0 >> 12, t0 = gm0 & 4095;
          ushort4 pk;
          pk.x = f2bu(acc[mi][ni][0] + bs);
          pk.y = f2bu(acc[mi][ni][1] + bs);
          pk.z = f2bu(acc[mi][ni][2] + bs);
          pk.w = f2bu(acc[mi][ni][3] + bs);
          *(ushort4*)&v[(((size_t)(b0 * NH + hh)) * DH + d) * TSEQ + t0] = pk;
        } else {
          uint16_t* dst = which ? k : q;
          float sc = which ? 1.0f : 0.1803368801111204f;  // 0.125 * log2(e)
          #pragma unroll
          for (int j = 0; j < 4; ++j) {
            int gm = gm0 + j;
            int bb = gm >> 12, t = gm & 4095;
            float val = (acc[mi][ni][j] + bs) * sc;
            dst[(((size_t)(bb * NH + hh)) * TSEQ + t) * DH + d] = f2bu(val);
          }
        }
      } else {
        #pragma unroll
        for (int j = 0; j < 4; ++j) {
          int gm = mb + wr + mi * 16 + lg * 4 + j;
          int gn = nb + wc + ni * 16 + lr;
          outf[(size_t)gm * N + gn] = acc[mi][ni][j] + bias[gn];
        }
      }
    }
  }
}

// ---------------- flash attention (causal), paired q-tiles, swizzled LDS ----------------
// Q pre-scaled by 0.125*log2e -> softmax in exp2 domain.
// LDS layout for Ks/Vs/Ps: 16B chunk c of row r stored at slot c^(r&7) (rows are 128B).
__global__ __launch_bounds__(256) void attn_fwd(
    const uint16_t* __restrict__ Q, const uint16_t* __restrict__ K,
    const uint16_t* __restrict__ Vt, uint16_t* __restrict__ O) {
  int bh = blockIdx.y;
  int b = bh / NH, h = bh - b * NH;
  size_t base = (size_t)bh * TSEQ * DH;
  int tid = threadIdx.x, w = tid >> 6, l = tid & 63;
  int lg = l >> 4, lr = l & 15;
  __shared__ uint16_t Ks[64 * 64];
  __shared__ uint16_t Vs[64 * 64];
  __shared__ uint16_t Ps[4][16 * 64];
  char* pw = (char*)Ps[w];
  // pre-swizzled global source for linear global_load_lds dest (rule: swizzle source+read)
  int srow = tid >> 3;                       // 0..31
  int schunk = (tid & 7) ^ (srow & 7);
  const uint16_t* Kg0 = K + base + (size_t)srow * DH + schunk * 8;
  const uint16_t* Vg0 = Vt + base + (size_t)srow * TSEQ + schunk * 8;
  char* KsB = (char*)Ks + w * 1024;
  char* VsB = (char*)Vs + w * 1024;
  int swzA = (lg ^ (lr & 7)) << 4;   // byte offset of chunk lg in row with row&7==lr&7
  int swzB = swzA ^ 64;              // chunk lg+4
  for (int rep = 0; rep < 2; ++rep) {
    int qt = rep ? (63 - (int)blockIdx.x) : (int)blockIdx.x;
    int qbase = qt * 64;
    int qrow = qbase + w * 16 + lr;
    bf16x8 qf0 = *(const bf16x8_a*)(const void*)(Q + base + (size_t)qrow * DH + lg * 8);
    bf16x8 qf1 = *(const bf16x8_a*)(const void*)(Q + base + (size_t)qrow * DH + 32 + lg * 8);
    f32x4 oacc[4] = {};
    float mj[4] = {-1e30f, -1e30f, -1e30f, -1e30f};
    float lj[4] = {0.f, 0.f, 0.f, 0.f};
    for (int kt = 0; kt <= qt; ++kt) {
      __syncthreads();
      gload_lds16(Kg0 + (size_t)kt * (64 * DH), KsB);
      gload_lds16(Kg0 + (size_t)kt * (64 * DH) + 32 * DH, KsB + 4096);
      gload_lds16(Vg0 + (size_t)kt * 64, VsB);
      gload_lds16(Vg0 + (size_t)kt * 64 + (size_t)32 * TSEQ, VsB + 4096);
      __syncthreads();
      // S = Q @ K^T (exp2 domain; Q pre-scaled)
      f32x4 sacc[4];
      #pragma unroll
      for (int ni = 0; ni < 4; ++ni) {
        const char* kb = (const char*)Ks + (ni * 16 + lr) * 128;
        bf16x8 kf0 = *(const bf16x8_a*)(kb + swzA);
        bf16x8 kf1 = *(const bf16x8_a*)(kb + swzB);
        f32x4 s = {};
        s = __builtin_amdgcn_mfma_f32_16x16x32_bf16(qf0, kf0, s, 0, 0, 0);
        s = __builtin_amdgcn_mfma_f32_16x16x32_bf16(qf1, kf1, s, 0, 0, 0);
        sacc[ni] = s;
      }
      float rowmax[4];
      if (kt == qt) {  // diagonal tile: apply causal mask
        rowmax[0] = rowmax[1] = rowmax[2] = rowmax[3] = -1e30f;
        int qg0 = qbase + w * 16 + lg * 4;
        #pragma unroll
        for (int ni = 0; ni < 4; ++ni) {
          int kg = kt * 64 + ni * 16 + lr;
          #pragma unroll
          for (int j = 0; j < 4; ++j) {
            float sv = (kg <= qg0 + j) ? sacc[ni][j] : -1e30f;
            sacc[ni][j] = sv;
            rowmax[j] = fmaxf(rowmax[j], sv);
          }
        }
      } else {
        #pragma unroll
        for (int j = 0; j < 4; ++j)
          rowmax[j] = fmaxf(fmaxf(sacc[0][j], sacc[1][j]), fmaxf(sacc[2][j], sacc[3][j]));
      }
      #pragma unroll
      for (int j = 0; j < 4; ++j)
        #pragma unroll
        for (int msk = 1; msk < 16; msk <<= 1)
          rowmax[j] = fmaxf(rowmax[j], __shfl_xor(rowmax[j], msk, 64));
      float g = fmaxf(fmaxf(rowmax[0] - mj[0], rowmax[1] - mj[1]),
                      fmaxf(rowmax[2] - mj[2], rowmax[3] - mj[3]));
      if (__any(g > 8.f)) {  // defer-max: skip rescale when max barely grows
        #pragma unroll
        for (int j = 0; j < 4; ++j) {
          float mn = fmaxf(mj[j], rowmax[j]);
          float c = exp2f(mj[j] - mn);
          mj[j] = mn;
          lj[j] *= c;
          #pragma unroll
          for (int nd = 0; nd < 4; ++nd) oacc[nd][j] *= c;
        }
      }
      // P = exp2(S - m); store swizzled into per-wave LDS tile [16 q][64 k]
      #pragma unroll
      for (int ni = 0; ni < 4; ++ni) {
        int chunkbase = ni * 2 + (lr >> 3);
        int bofs = (lr & 7) * 2;
        #pragma unroll
        for (int j = 0; j < 4; ++j) {
          float p = exp2f(sacc[ni][j] - mj[j]);
          lj[j] += p;  // per-lane partial; reduced once at the end
          int q8 = (lg & 1) * 4 + j;
          *(__bf16*)(pw + (lg * 4 + j) * 128 + ((chunkbase ^ q8) << 4) + bofs) = (__bf16)p;
        }
      }
      bf16x8 pf0 = *(const bf16x8_a*)(pw + lr * 128 + swzA);
      bf16x8 pf1 = *(const bf16x8_a*)(pw + lr * 128 + swzB);
      #pragma unroll
      for (int nd = 0; nd < 4; ++nd) {
        const char* vb = (const char*)Vs + (nd * 16 + lr) * 128;
        bf16x8 vf0 = *(const bf16x8_a*)(vb + swzA);
        bf16x8 vf1 = *(const bf16x8_a*)(vb + swzB);
        oacc[nd] = __builtin_amdgcn_mfma_f32_16x16x32_bf16(pf0, vf0, oacc[nd], 0, 0, 0);
        oacc[nd] = __builtin_amdgcn_mfma_f32_16x16x32_bf16(pf1, vf1, oacc[nd], 0, 0, 0);
      }
    }
    #pragma unroll
    for (int j = 0; j < 4; ++j)
      #pragma unroll
      for (int msk = 1; msk < 16; msk <<= 1) lj[j] += __shfl_xor(lj[j], msk, 64);
    #pragma unroll
    for (int nd = 0; nd < 4; ++nd) {
      #pragma unroll
      for (int j = 0; j < 4; ++j) {
        int t = qbase + w * 16 + lg * 4 + j;
        float val = oacc[nd][j] / lj[j];
        O[((size_t)(b * TSEQ + t)) * CDIM + h * DH + nd * 16 + lr] = f2bu(val);
      }
    }
  }
}

extern "C" void kernel_launch(void* const* d_in, const int* in_sizes, int n_in,
                              void* d_out, int out_size, void* d_ws, size_t ws_size,
                              hipStream_t stream) {
  const float* x    = (const float*)d_in[0];
  const float* Wqkv = (const float*)d_in[1];
  const float* bqkv = (const float*)d_in[2];
  const float* Wout = (const float*)d_in[3];
  const float* bout = (const float*)d_in[4];
  float* out = (float*)d_out;
  char* ws = (char*)d_ws;

  uint16_t* Xb    = (uint16_t*)(ws + 0);          // 8192*768*2   = 12,582,912
  uint16_t* Wqkvt = (uint16_t*)(ws + 12582912);   // 2304*768*2   =  3,538,944
  uint16_t* Woutt = (uint16_t*)(ws + 16121856);   // 768*768*2    =  1,179,648
  uint16_t* Qb    = (uint16_t*)(ws + 17301504);   // 12,582,912 (pre-scaled)
  uint16_t* Kb    = (uint16_t*)(ws + 29884416);   // 12,582,912
  uint16_t* Vtb   = (uint16_t*)(ws + 42467328);   // 12,582,912 (V^T [B,H,Dh,T])
  uint16_t* Ob    = (uint16_t*)(ws + 55050240);   // 12,582,912 (end 67,633,152)

  cast_f32_bf16<<<2048, 256, 0, stream>>>(x, Xb, (MROWS * CDIM) / 4);
  transpose_cast<<<dim3(24, 72), 256, 0, stream>>>(Wqkv, Wqkvt, 768, 2304);
  transpose_cast<<<dim3(24, 24), 256, 0, stream>>>(Wout, Woutt, 768, 768);
  gemm_bt<0><<<dim3(64, 18), 256, 0, stream>>>(Xb, Wqkvt, bqkv, Qb, Kb, Vtb, nullptr, 2304, 768);
  attn_fwd<<<dim3(32, 24), 256, 0, stream>>>(Qb, Kb, Vtb, Ob);
  gemm_bt<1><<<dim3(64, 6), 256, 0, stream>>>(Ob, Woutt, bout, nullptr, nullptr, nullptr, out, 768, 768);
}